// Round 7
// baseline (292.135 us; speedup 1.0000x reference)
//
#include <hip/hip_runtime.h>
#include <stdint.h>

#define M_DIM 8192
#define N_DIM 4096
#define K_DIM 4096

typedef float f32x4 __attribute__((ext_vector_type(4)));
typedef int   i32x4 __attribute__((ext_vector_type(4)));
typedef int   i32x8 __attribute__((ext_vector_type(8)));

// ---------------- fused amax (x and w) via uint-bits atomicMax ----------------
__global__ __launch_bounds__(256) void amax2_kernel(const float* __restrict__ x,
                                                    const float* __restrict__ wgt,
                                                    unsigned int* __restrict__ ws_u) {
    const int which = blockIdx.y;
    const float4* p = (const float4*)(which ? wgt : x);
    const int n4 = (which ? N_DIM : M_DIM) * (K_DIM / 4);
    int tid = blockIdx.x * blockDim.x + threadIdx.x;
    int stride = gridDim.x * blockDim.x;
    float m = 0.0f;
    for (int i = tid; i < n4; i += stride) {
        float4 v = p[i];
        m = fmaxf(m, fmaxf(fmaxf(fabsf(v.x), fabsf(v.y)),
                           fmaxf(fabsf(v.z), fabsf(v.w))));
    }
#pragma unroll
    for (int off = 32; off > 0; off >>= 1)
        m = fmaxf(m, __shfl_down(m, off, 64));
    __shared__ float sm[4];
    if ((threadIdx.x & 63) == 0) sm[threadIdx.x >> 6] = m;
    __syncthreads();
    if (threadIdx.x == 0) {
        m = fmaxf(fmaxf(sm[0], sm[1]), fmaxf(sm[2], sm[3]));
        atomicMax(ws_u + which, __float_as_uint(m));  // values >= 0: bit order == float order
    }
}

// ---------------- fused quantize f32 -> fp8 e4m3fn (packed 4/uint) -------------
__global__ __launch_bounds__(256) void quant2_kernel(const float* __restrict__ x,
                                                     const float* __restrict__ wgt,
                                                     unsigned int* __restrict__ xq,
                                                     unsigned int* __restrict__ wq,
                                                     const unsigned int* __restrict__ ws_u) {
    const int which = blockIdx.y;
    const float4* p = (const float4*)(which ? wgt : x);
    unsigned int* outp = which ? wq : xq;
    const int n4 = (which ? N_DIM : M_DIM) * (K_DIM / 4);
    float amax = fmaxf(__uint_as_float(ws_u[which]), 1e-12f);
    float scale = 448.0f / amax;
    int tid = blockIdx.x * blockDim.x + threadIdx.x;
    int stride = gridDim.x * blockDim.x;
    for (int i = tid; i < n4; i += stride) {
        float4 v = p[i];
        float a = fminf(fmaxf(v.x * scale, -448.0f), 448.0f);
        float b = fminf(fmaxf(v.y * scale, -448.0f), 448.0f);
        float c = fminf(fmaxf(v.z * scale, -448.0f), 448.0f);
        float d = fminf(fmaxf(v.w * scale, -448.0f), 448.0f);
        int w = __builtin_amdgcn_cvt_pk_fp8_f32(a, b, 0, false);
        w = __builtin_amdgcn_cvt_pk_fp8_f32(c, d, w, true);
        outp[i] = (unsigned int)w;
    }
}

// ---------------- MX-fp8 GEMM: A via LDS, B direct-to-register ----------------
__device__ __forceinline__ void gld16(const void* g, void* l) {
    __builtin_amdgcn_global_load_lds(
        (const __attribute__((address_space(1))) void*)g,
        (__attribute__((address_space(3))) void*)l, 16, 0, 0);
}

#define MFMA_MX(a, b, c) __builtin_amdgcn_mfma_scale_f32_16x16x128_f8f6f4( \
    (a), (b), (c), 0, 0, 0, 0x7F7F7F7F, 0, 0x7F7F7F7F)
#define BAR()    __builtin_amdgcn_s_barrier()
#define VMCNT(n) asm volatile("s_waitcnt vmcnt(" #n ")" ::: "memory")
#define PRIO1()  __builtin_amdgcn_s_setprio(1)
#define PRIO0()  __builtin_amdgcn_s_setprio(0)

// A LDS: dbuf 2 x 32KB, tile [256 rows][128 B], 16B-chunk XOR swizzle
// (chunk ^= row&7); linear dest, pre-swizzled global source, XOR on read
// (rule #21). B: NO LDS — per-lane 32B global loads straight to registers
// (rows are block-shared -> L2 hits), double-buffered b0/b1 with static
// macro references (rule #20).
// vmcnt ledger (1 op = 16B): steady 8 outstanding (B(t) frag loads).
// Per tile: issue 4 A-stages + 8 B-loads -> 20; VMCNT(12) retires B(t)
// before its MFMAs; VMCNT(8) at end retires A(t+1); ONE barrier per tile
// (1 block/CU -> overlap comes from wave skew; fewer barriers = more skew).
#define TILE_BODY(T, BC, BN)                                                   \
  {                                                                            \
    const uint8_t* lab = &lds[((T) & 1) * 32768];                              \
    const int nb = (((T) & 1) ^ 1);                                            \
    const int kn = ((T) + 1) * 128;                                            \
    stA(nb, kn, 0);   stA(nb, kn, 64);                                         \
    stA(nb, kn, 128); stA(nb, kn, 192);                                        \
    BN[0] = *(const i32x8*)(bP0 + kn);                                         \
    BN[1] = *(const i32x8*)(bP1 + kn);                                         \
    BN[2] = *(const i32x8*)(bP2 + kn);                                         \
    BN[3] = *(const i32x8*)(bP3 + kn);                                         \
    av[0] = ldf(lab, rowA0);      av[1] = ldf(lab, rowA0 + 16);                \
    av[2] = ldf(lab, rowA0 + 32); av[3] = ldf(lab, rowA0 + 48);                \
    VMCNT(12);                                                                 \
    PRIO1();                                                                   \
    acc[0][0] = MFMA_MX(av[0], BC[0], acc[0][0]);                              \
    acc[0][1] = MFMA_MX(av[0], BC[1], acc[0][1]);                              \
    acc[1][0] = MFMA_MX(av[1], BC[0], acc[1][0]);                              \
    acc[1][1] = MFMA_MX(av[1], BC[1], acc[1][1]);                              \
    acc[2][0] = MFMA_MX(av[2], BC[0], acc[2][0]);                              \
    acc[2][1] = MFMA_MX(av[2], BC[1], acc[2][1]);                              \
    acc[3][0] = MFMA_MX(av[3], BC[0], acc[3][0]);                              \
    acc[3][1] = MFMA_MX(av[3], BC[1], acc[3][1]);                              \
    acc[0][2] = MFMA_MX(av[0], BC[2], acc[0][2]);                              \
    acc[0][3] = MFMA_MX(av[0], BC[3], acc[0][3]);                              \
    acc[1][2] = MFMA_MX(av[1], BC[2], acc[1][2]);                              \
    acc[1][3] = MFMA_MX(av[1], BC[3], acc[1][3]);                              \
    acc[2][2] = MFMA_MX(av[2], BC[2], acc[2][2]);                              \
    acc[2][3] = MFMA_MX(av[2], BC[3], acc[2][3]);                              \
    acc[3][2] = MFMA_MX(av[3], BC[2], acc[3][2]);                              \
    acc[3][3] = MFMA_MX(av[3], BC[3], acc[3][3]);                              \
    PRIO0();                                                                   \
    av[0] = ldf(lab, rowA0 + 64); av[1] = ldf(lab, rowA0 + 80);                \
    av[2] = ldf(lab, rowA0 + 96); av[3] = ldf(lab, rowA0 + 112);               \
    PRIO1();                                                                   \
    acc[4][0] = MFMA_MX(av[0], BC[0], acc[4][0]);                              \
    acc[4][1] = MFMA_MX(av[0], BC[1], acc[4][1]);                              \
    acc[5][0] = MFMA_MX(av[1], BC[0], acc[5][0]);                              \
    acc[5][1] = MFMA_MX(av[1], BC[1], acc[5][1]);                              \
    acc[6][0] = MFMA_MX(av[2], BC[0], acc[6][0]);                              \
    acc[6][1] = MFMA_MX(av[2], BC[1], acc[6][1]);                              \
    acc[7][0] = MFMA_MX(av[3], BC[0], acc[7][0]);                              \
    acc[7][1] = MFMA_MX(av[3], BC[1], acc[7][1]);                              \
    acc[4][2] = MFMA_MX(av[0], BC[2], acc[4][2]);                              \
    acc[4][3] = MFMA_MX(av[0], BC[3], acc[4][3]);                              \
    acc[5][2] = MFMA_MX(av[1], BC[2], acc[5][2]);                              \
    acc[5][3] = MFMA_MX(av[1], BC[3], acc[5][3]);                              \
    acc[6][2] = MFMA_MX(av[2], BC[2], acc[6][2]);                              \
    acc[6][3] = MFMA_MX(av[2], BC[3], acc[6][3]);                              \
    acc[7][2] = MFMA_MX(av[3], BC[2], acc[7][2]);                              \
    acc[7][3] = MFMA_MX(av[3], BC[3], acc[7][3]);                              \
    PRIO0();                                                                   \
    VMCNT(8);                                                                  \
    BAR();                                                                     \
  }

__global__ __launch_bounds__(512, 2) void gemm_fp8_kernel(
    const uint8_t* __restrict__ Aq,   // [M][K] fp8
    const uint8_t* __restrict__ Bq,   // [N][K] fp8
    const float* __restrict__ bias,   // [N]
    const unsigned int* __restrict__ ws_u,
    float* __restrict__ out)          // [M][N] f32
{
    __shared__ uint8_t lds[65536];

    const int tid = threadIdx.x;
    const int w = tid >> 6, l = tid & 63;

    // XCD swizzle (512 blocks, %8==0): 32 M-tiles x 16 N-tiles
    const int cpx = (int)gridDim.x >> 3;
    const int bid = (int)blockIdx.x;
    const int swz = (bid & 7) * cpx + (bid >> 3);
    const int bm = swz >> 4, bn = swz & 15;

    const uint8_t* gA = Aq + (size_t)bm * 256 * K_DIM;

    // A staging: thread t -> rows idx+{0,64,128,192}; dest chunk p; src p^(row&7)
    const int idx = tid >> 3, p = tid & 7;
    const int srcX = ((p ^ (idx & 7)) << 4);
    const uint8_t* aRow = gA + (size_t)idx * K_DIM + srcX;
    const int dA = tid * 16;

    // fragment constants
    const int wr = w >> 2, wc = w & 3;       // 2M x 4N wave grid, 128x64 per wave
    const int lr = l & 15, g = l >> 4;
    const int oLo = (((2 * g) ^ (lr & 7)) << 4);
    const int oHi = (((2 * g + 1) ^ (lr & 7)) << 4);
    const int rowA0 = wr * 128 + lr;

    // B direct-load pointers: lane reads rows bn*256+wc*64+n*16+lr, col g*32
    const uint8_t* bBase = Bq + (size_t)(bn * 256 + wc * 64 + lr) * K_DIM + g * 32;
    const uint8_t* bP0 = bBase;
    const uint8_t* bP1 = bBase + (size_t)16 * K_DIM;
    const uint8_t* bP2 = bBase + (size_t)32 * K_DIM;
    const uint8_t* bP3 = bBase + (size_t)48 * K_DIM;

    auto stA = [&](int bb, int kn, int rbase) {
        gld16(aRow + (size_t)rbase * K_DIM + kn,
              &lds[bb * 32768 + rbase * 128 + dA]);
    };
    auto ldf = [&](const uint8_t* base, int row) -> i32x8 {
        const uint8_t* q = base + (row << 7);
        i32x4 lo = *(const i32x4*)(q + oLo);
        i32x4 hi = *(const i32x4*)(q + oHi);
        return __builtin_shufflevector(lo, hi, 0, 1, 2, 3, 4, 5, 6, 7);
    };

    f32x4 acc[8][4] = {};
    i32x8 av[4];
    i32x8 b0[4], b1[4];

    // prologue: stage A(0) (4 ops), load B(0) (8 ops) -> 12 outstanding;
    // VMCNT(8) retires A(0) (oldest 4), leaves the 8 B(0) -> loop invariant.
    stA(0, 0, 0);   stA(0, 0, 64);
    stA(0, 0, 128); stA(0, 0, 192);
    b0[0] = *(const i32x8*)(bP0);
    b0[1] = *(const i32x8*)(bP1);
    b0[2] = *(const i32x8*)(bP2);
    b0[3] = *(const i32x8*)(bP3);
    VMCNT(8); BAR();

    for (int t = 0; t < 30; t += 2) {
        TILE_BODY(t, b0, b1);
        TILE_BODY(t + 1, b1, b0);
    }
    TILE_BODY(30, b0, b1);   // stages A(31), loads B(31) -> b1

    // peeled last tile t=31 (buf 1): nothing to prefetch; drain
    {
        const uint8_t* lab = &lds[32768];
        av[0] = ldf(lab, rowA0);      av[1] = ldf(lab, rowA0 + 16);
        av[2] = ldf(lab, rowA0 + 32); av[3] = ldf(lab, rowA0 + 48);
        VMCNT(0);
#pragma unroll
        for (int m = 0; m < 4; ++m) {
            acc[m][0] = MFMA_MX(av[m], b1[0], acc[m][0]);
            acc[m][1] = MFMA_MX(av[m], b1[1], acc[m][1]);
            acc[m][2] = MFMA_MX(av[m], b1[2], acc[m][2]);
            acc[m][3] = MFMA_MX(av[m], b1[3], acc[m][3]);
        }
        av[0] = ldf(lab, rowA0 + 64); av[1] = ldf(lab, rowA0 + 80);
        av[2] = ldf(lab, rowA0 + 96); av[3] = ldf(lab, rowA0 + 112);
#pragma unroll
        for (int m = 0; m < 4; ++m) {
            acc[4 + m][0] = MFMA_MX(av[m], b1[0], acc[4 + m][0]);
            acc[4 + m][1] = MFMA_MX(av[m], b1[1], acc[4 + m][1]);
            acc[4 + m][2] = MFMA_MX(av[m], b1[2], acc[4 + m][2]);
            acc[4 + m][3] = MFMA_MX(av[m], b1[3], acc[4 + m][3]);
        }
    }

    // ---- epilogue: scale by (amax_x/448)*(amax_w/448), add bias
    const float ax = fmaxf(__uint_as_float(ws_u[0]), 1e-12f);
    const float aw = fmaxf(__uint_as_float(ws_u[1]), 1e-12f);
    const float inv = (ax * (1.0f / 448.0f)) * (aw * (1.0f / 448.0f));

    const int orow0 = bm * 256 + wr * 128 + g * 4;   // D: row=(lane>>4)*4+reg
    const int ocol0 = bn * 256 + wc * 64 + lr;       // D: col=lane&15
#pragma unroll
    for (int mb = 0; mb < 8; ++mb) {
#pragma unroll
        for (int nb2 = 0; nb2 < 4; ++nb2) {
            const int col = ocol0 + nb2 * 16;
            const float bvv = bias[col];
#pragma unroll
            for (int j = 0; j < 4; ++j) {
                const int row = orow0 + mb * 16 + j;
                out[(size_t)row * N_DIM + col] = acc[mb][nb2][j] * inv + bvv;
            }
        }
    }
}

// ---------------- launch ----------------
extern "C" void kernel_launch(void* const* d_in, const int* in_sizes, int n_in,
                              void* d_out, int out_size, void* d_ws, size_t ws_size,
                              hipStream_t stream) {
    const float* x    = (const float*)d_in[0];   // [8192, 4096]
    const float* wgt  = (const float*)d_in[1];   // [4096, 4096]
    const float* bias = (const float*)d_in[2];   // [4096]
    float* out = (float*)d_out;                  // [8192, 4096] f32

    unsigned int* ws_u = (unsigned int*)d_ws;
    uint8_t* xq = (uint8_t*)d_ws + 256;
    uint8_t* wq = xq + (size_t)M_DIM * K_DIM;

    hipMemsetAsync(d_ws, 0, 8, stream);          // zero both amax slots

    dim3 ga(1024, 2);
    amax2_kernel<<<ga, 256, 0, stream>>>(x, wgt, ws_u);

    dim3 gq(2048, 2);
    quant2_kernel<<<gq, 256, 0, stream>>>(x, wgt, (unsigned int*)xq,
                                          (unsigned int*)wq, ws_u);

    gemm_fp8_kernel<<<(M_DIM / 256) * (N_DIM / 256), 512, 0, stream>>>(
        xq, wq, bias, ws_u, out);
}